// Round 1
// baseline (5428.469 us; speedup 1.0000x reference)
//
#include <hip/hip_runtime.h>
#include <math.h>

#define T_TOK 2048
#define HID   4096
#define NH    32
#define NKV   8
#define HD    128
#define QKVD  6144   // (NH + 2*NKV) * HD

// ---------------- wave helpers (wave64) ----------------
__device__ __forceinline__ float wave_sum(float v) {
  for (int off = 32; off; off >>= 1) v += __shfl_xor(v, off, 64);
  return v;
}
__device__ __forceinline__ float wave_max(float v) {
  for (int off = 32; off; off >>= 1) v = fmaxf(v, __shfl_xor(v, off, 64));
  return v;
}
__device__ __forceinline__ float wave_min(float v) {
  for (int off = 32; off; off >>= 1) v = fminf(v, __shfl_xor(v, off, 64));
  return v;
}

// ---------------- K1: bilinear (lnL^T X lnR) + 8-bit sym fake-quant per token ----------------
__global__ __launch_bounds__(256) void k_bilinear_quant(
    const float* __restrict__ hidden, const float* __restrict__ lnL,
    const float* __restrict__ lnR, float* __restrict__ xq)
{
  __shared__ float sX[4096];
  __shared__ float sT[4096];
  __shared__ float sL[4096];
  __shared__ float sR[4096];
  __shared__ float sm[4];
  const int t = blockIdx.x;
  const int tid = threadIdx.x;
  const float* src = hidden + (size_t)t * 4096;
  for (int i = tid; i < 4096; i += 256) { sX[i] = src[i]; sL[i] = lnL[i]; sR[i] = lnR[i]; }
  __syncthreads();
  // tmp[l,R] = sum_r X[l,r] * lnR[r,R]
  #pragma unroll
  for (int u = 0; u < 16; u++) {
    int p = tid + 256 * u;
    int l = p >> 6, R = p & 63;
    float a = 0.f;
    #pragma unroll 8
    for (int r = 0; r < 64; r++) a += sX[(l << 6) + r] * sR[(r << 6) + R];
    sT[p] = a;
  }
  __syncthreads();
  // out[L,R] = sum_l lnL[l,L] * tmp[l,R]
  float vals[16];
  float amax = 0.f;
  #pragma unroll
  for (int u = 0; u < 16; u++) {
    int p = tid + 256 * u;
    int L = p >> 6, R = p & 63;
    float a = 0.f;
    #pragma unroll 8
    for (int l = 0; l < 64; l++) a += sL[(l << 6) + L] * sT[(l << 6) + R];
    vals[u] = a;
    amax = fmaxf(amax, fabsf(a));
  }
  amax = wave_max(amax);
  if ((tid & 63) == 0) sm[tid >> 6] = amax;
  __syncthreads();
  amax = fmaxf(fmaxf(sm[0], sm[1]), fmaxf(sm[2], sm[3]));
  float scale = fmaxf(amax * (1.0f / 127.0f), 1e-8f);
  #pragma unroll
  for (int u = 0; u < 16; u++) {
    int p = tid + 256 * u;
    float q = rintf(vals[u] / scale);           // jnp.round = half-even = rintf
    q = fminf(fmaxf(q, -128.f), 127.f);
    xq[(size_t)t * 4096 + p] = q * scale;
  }
}

// ---------------- GEMM: C[m][n] = sum_k A[m][k] * B[n][k]  (both K-contiguous) ----------------
__global__ __launch_bounds__(256) void k_gemm_bt(
    const float* __restrict__ A, const float* __restrict__ B, float* __restrict__ C,
    int M, int N, int K)
{
  __shared__ float sA[16][68];
  __shared__ float sB[16][68];
  const int tid = threadIdx.x;
  const int tx = tid & 15, ty = tid >> 4;
  const int bm = blockIdx.y << 6, bn = blockIdx.x << 6;
  const int lr = tid >> 2;
  const int lc = (tid & 3) << 2;
  const float* Ap = A + (size_t)(bm + lr) * K + lc;
  const float* Bp = B + (size_t)(bn + lr) * K + lc;
  float acc[4][4] = {{0.f}};
  for (int k0 = 0; k0 < K; k0 += 16) {
    float4 a4 = *(const float4*)(Ap + k0);
    float4 b4 = *(const float4*)(Bp + k0);
    __syncthreads();
    sA[lc + 0][lr] = a4.x; sA[lc + 1][lr] = a4.y; sA[lc + 2][lr] = a4.z; sA[lc + 3][lr] = a4.w;
    sB[lc + 0][lr] = b4.x; sB[lc + 1][lr] = b4.y; sB[lc + 2][lr] = b4.z; sB[lc + 3][lr] = b4.w;
    __syncthreads();
    #pragma unroll
    for (int k = 0; k < 16; k++) {
      float4 av = *(const float4*)&sA[k][ty << 2];
      float4 bv = *(const float4*)&sB[k][tx << 2];
      float am[4] = {av.x, av.y, av.z, av.w};
      float bb[4] = {bv.x, bv.y, bv.z, bv.w};
      #pragma unroll
      for (int i = 0; i < 4; i++)
        #pragma unroll
        for (int j = 0; j < 4; j++)
          acc[i][j] += am[i] * bb[j];
    }
  }
  #pragma unroll
  for (int i = 0; i < 4; i++) {
    float4 o; o.x = acc[i][0]; o.y = acc[i][1]; o.z = acc[i][2]; o.w = acc[i][3];
    *(float4*)(C + (size_t)(bm + (ty << 2) + i) * N + bn + (tx << 2)) = o;
  }
}

// ---------------- Q/K processing: rmsnorm -> rope -> @k_trans (-> 4-bit asym quant for K) ----------------
// one wave per (t, head); lane holds dims (lane, lane+64)
__global__ __launch_bounds__(64) void k_qkproc(
    const float* __restrict__ qkv, const int* __restrict__ pos,
    const float* __restrict__ nw, const float* __restrict__ kt,
    float* __restrict__ dst_, int nheads, int off_n, int do_quant)
{
  const int h = blockIdx.x, t = blockIdx.y;
  const int lane = threadIdx.x;
  const float* src = qkv + (size_t)t * QKVD + off_n + h * HD;
  float x1 = src[lane], x2 = src[lane + 64];
  float ss = wave_sum(x1 * x1 + x2 * x2);
  float rinv = 1.0f / sqrtf(ss * (1.0f / 128.0f) + 1e-6f);
  x1 *= rinv * nw[lane];
  x2 *= rinv * nw[lane + 64];
  // rope: lane = half-dim index j; x1 = x[j], x2 = x[j+64]
  const float p = (float)pos[t];
  const float invf = exp2f((float)lane * (-19.931568569324174f / 64.0f)); // theta^{-j/64}
  const float fr = p * invf;
  const float c = cosf(fr), s = sinf(fr);
  const float y1 = x1 * c - x2 * s;
  const float y2 = x2 * c + x1 * s;
  __shared__ float sq[128];
  sq[lane] = y1; sq[lane + 64] = y2;
  __syncthreads();
  // out[d] = sum_e y[e] * k_trans[e][d]   (== q @ inv(k_trans).T since k_trans orthogonal)
  float o1 = 0.f, o2 = 0.f;
  #pragma unroll 8
  for (int e = 0; e < 128; e++) {
    float qe = sq[e];
    o1 += qe * kt[(e << 7) + lane];
    o2 += qe * kt[(e << 7) + 64 + lane];
  }
  if (do_quant) {  // 4-bit group-asym, group = 128 = whole head vector
    float mn = fminf(wave_min(fminf(o1, o2)), 0.f);
    float mx = fmaxf(wave_max(fmaxf(o1, o2)), 0.f);
    float scale = fmaxf((mx - mn) * (1.0f / 15.0f), 1e-8f);
    float zero = rintf(-mn / scale);
    float q1 = fminf(fmaxf(rintf(o1 / scale) + zero, 0.f), 15.f);
    float q2 = fminf(fmaxf(rintf(o2 / scale) + zero, 0.f), 15.f);
    o1 = (q1 - zero) * scale;
    o2 = (q2 - zero) * scale;
  }
  float* d = dst_ + ((size_t)t * nheads + h) * HD;
  d[lane] = o1; d[lane + 64] = o2;
}

// ---------------- V: 4-bit group-asym quant straight from qkv ----------------
__global__ __launch_bounds__(64) void k_vproc(const float* __restrict__ qkv, float* __restrict__ vp)
{
  const int h = blockIdx.x, t = blockIdx.y;
  const int lane = threadIdx.x;
  const float* src = qkv + (size_t)t * QKVD + (NH * HD + NKV * HD) + h * HD;
  float o1 = src[lane], o2 = src[lane + 64];
  float mn = fminf(wave_min(fminf(o1, o2)), 0.f);
  float mx = fmaxf(wave_max(fmaxf(o1, o2)), 0.f);
  float scale = fmaxf((mx - mn) * (1.0f / 15.0f), 1e-8f);
  float zero = rintf(-mn / scale);
  float q1 = fminf(fmaxf(rintf(o1 / scale) + zero, 0.f), 15.f);
  float q2 = fminf(fmaxf(rintf(o2 / scale) + zero, 0.f), 15.f);
  float* d = vp + ((size_t)t * NKV + h) * HD;
  d[lane] = (q1 - zero) * scale;
  d[lane + 64] = (q2 - zero) * scale;
}

// ---------------- flash attention, causal, GQA rep=4, f32 ----------------
// block 256 thr handles (head, 64 q-rows); thread (r = tid>>2, c4 = tid&3) owns
// scores s = c4+4j and output dims [c4*32, c4*32+32)
__global__ __launch_bounds__(256) void k_attn(
    const float* __restrict__ qp, const float* __restrict__ kp,
    const float* __restrict__ vp, float* __restrict__ ao)
{
  const int qb = blockIdx.x;
  const int h  = blockIdx.y;
  const int kvh = h >> 2;
  const int q0 = qb * 64;
  __shared__ float sQ[64][132];
  __shared__ float sK[64][132];
  __shared__ float sV[64][132];
  __shared__ float sS[64][68];
  const int tid = threadIdx.x;
  const int r = tid >> 2;
  const int c4 = tid & 3;
  const int d0 = c4 * 32;
  for (int i = tid; i < 64 * 32; i += 256) {
    int rr = i >> 5, ec = i & 31;
    *(float4*)&sQ[rr][ec * 4] = *(const float4*)(qp + ((size_t)(q0 + rr) * NH + h) * HD + ec * 4);
  }
  float4 acc[8];
  #pragma unroll
  for (int x = 0; x < 8; x++) acc[x] = make_float4(0.f, 0.f, 0.f, 0.f);
  float m_i = -1e30f, l_i = 0.f;
  const float sm_scale = 0.08838834764831845f;  // 128^-0.5
  for (int s0 = 0; s0 < q0 + 64; s0 += 64) {
    for (int i = tid; i < 64 * 32; i += 256) {
      int ssr = i >> 5, ec = i & 31;
      size_t base = ((size_t)(s0 + ssr) * NKV + kvh) * HD + ec * 4;
      *(float4*)&sK[ssr][ec * 4] = *(const float4*)(kp + base);
      *(float4*)&sV[ssr][ec * 4] = *(const float4*)(vp + base);
    }
    __syncthreads();
    float sc[16];
    #pragma unroll
    for (int j = 0; j < 16; j++) sc[j] = 0.f;
    for (int ec = 0; ec < 32; ec++) {
      float4 qv = *(const float4*)&sQ[r][ec * 4];
      #pragma unroll
      for (int j = 0; j < 16; j++) {
        float4 kv = *(const float4*)&sK[c4 + 4 * j][ec * 4];
        sc[j] += qv.x * kv.x + qv.y * kv.y + qv.z * kv.z + qv.w * kv.w;
      }
    }
    float mx = -1e30f;
    #pragma unroll
    for (int j = 0; j < 16; j++) {
      int sg = s0 + c4 + 4 * j;
      sc[j] = (sg <= q0 + r) ? sc[j] * sm_scale : -1e30f;
      mx = fmaxf(mx, sc[j]);
    }
    mx = fmaxf(mx, __shfl_xor(mx, 1, 64));
    mx = fmaxf(mx, __shfl_xor(mx, 2, 64));
    float m_new = fmaxf(m_i, mx);
    float lsum = 0.f;
    #pragma unroll
    for (int j = 0; j < 16; j++) {
      float pj = expf(sc[j] - m_new);   // masked -> exp(-huge) = 0
      sS[r][c4 + 4 * j] = pj;
      lsum += pj;
    }
    lsum += __shfl_xor(lsum, 1, 64);
    lsum += __shfl_xor(lsum, 2, 64);
    float alpha = expf(m_i - m_new);
    l_i = l_i * alpha + lsum;
    m_i = m_new;
    #pragma unroll
    for (int x = 0; x < 8; x++) {
      acc[x].x *= alpha; acc[x].y *= alpha; acc[x].z *= alpha; acc[x].w *= alpha;
    }
    __syncthreads();
    for (int sgl = 0; sgl < 64; sgl++) {
      float pj = sS[r][sgl];
      const float4* vrow = (const float4*)&sV[sgl][d0];
      #pragma unroll
      for (int x = 0; x < 8; x++) {
        float4 vv = vrow[x];
        acc[x].x += pj * vv.x; acc[x].y += pj * vv.y;
        acc[x].z += pj * vv.z; acc[x].w += pj * vv.w;
      }
    }
    __syncthreads();
  }
  float linv = 1.0f / l_i;
  float* dst = ao + ((size_t)(q0 + r) * NH + h) * HD + d0;
  #pragma unroll
  for (int x = 0; x < 8; x++) {
    float4 o = acc[x];
    o.x *= linv; o.y *= linv; o.z *= linv; o.w *= linv;
    *(float4*)(dst + x * 4) = o;
  }
}

// ---------------- head mix (o_trans^T over heads) + 8-bit sym fake-quant per token ----------------
__global__ __launch_bounds__(256) void k_mix_quant(
    const float* __restrict__ ao, const float* __restrict__ ot, float* __restrict__ qo)
{
  __shared__ float sA[4096];
  __shared__ float sO[1024];
  __shared__ float sm[4];
  const int t = blockIdx.x;
  const int tid = threadIdx.x;
  for (int i = tid; i < 4096; i += 256) sA[i] = ao[(size_t)t * 4096 + i];
  for (int i = tid; i < 1024; i += 256) sO[i] = ot[i];
  __syncthreads();
  float vals[16];
  float amax = 0.f;
  #pragma unroll
  for (int u = 0; u < 16; u++) {
    int o = tid + 256 * u;
    int ih = o >> 7, d = o & 127;
    float a = 0.f;
    #pragma unroll 8
    for (int j = 0; j < 32; j++) a += sO[j * 32 + ih] * sA[j * 128 + d];
    vals[u] = a;
    amax = fmaxf(amax, fabsf(a));
  }
  amax = wave_max(amax);
  if ((tid & 63) == 0) sm[tid >> 6] = amax;
  __syncthreads();
  amax = fmaxf(fmaxf(sm[0], sm[1]), fmaxf(sm[2], sm[3]));
  float scale = fmaxf(amax * (1.0f / 127.0f), 1e-8f);
  #pragma unroll
  for (int u = 0; u < 16; u++) {
    int o = tid + 256 * u;
    float q = rintf(vals[u] / scale);
    q = fminf(fmaxf(q, -128.f), 127.f);
    qo[(size_t)t * 4096 + o] = q * scale;
  }
}

extern "C" void kernel_launch(void* const* d_in, const int* in_sizes, int n_in,
                              void* d_out, int out_size, void* d_ws, size_t ws_size,
                              hipStream_t stream) {
  const float* hidden    = (const float*)d_in[0];
  const int*   positions = (const int*)  d_in[1];
  const float* w_qkv     = (const float*)d_in[2];
  const float* w_o       = (const float*)d_in[3];
  const float* q_norm_w  = (const float*)d_in[4];
  const float* k_norm_w  = (const float*)d_in[5];
  const float* ln_left   = (const float*)d_in[6];
  const float* ln_right  = (const float*)d_in[7];
  const float* o_trans   = (const float*)d_in[8];
  const float* k_trans   = (const float*)d_in[9];
  float* out = (float*)d_out;
  char* ws = (char*)d_ws;

  // workspace layout (peak exactly 128 MiB), regions reused once dead:
  float* xq  = (float*)(ws);                    // 33,554,432 B  (T x 4096)   -> later reused as ao
  float* qkv = (float*)(ws + 33554432);         // 50,331,648 B  (T x 6144)   -> later reused as qo
  float* qp  = (float*)(ws + 83886080);         // 33,554,432 B  (T x 32 x 128)
  float* kp  = (float*)(ws + 117440512);        //  8,388,608 B  (T x 8 x 128)
  float* vp  = (float*)(ws + 125829120);        //  8,388,608 B  (T x 8 x 128)
  float* ao  = xq;                              // xq dead after QKV GEMM
  float* qo  = qkv;                             // qkv dead after q/k/v extraction

  k_bilinear_quant<<<T_TOK, 256, 0, stream>>>(hidden, ln_left, ln_right, xq);
  k_gemm_bt<<<dim3(QKVD / 64, T_TOK / 64), 256, 0, stream>>>(xq, w_qkv, qkv, T_TOK, QKVD, HID);
  k_qkproc<<<dim3(NH, T_TOK), 64, 0, stream>>>(qkv, positions, q_norm_w, k_trans, qp, NH, 0, 0);
  k_qkproc<<<dim3(NKV, T_TOK), 64, 0, stream>>>(qkv, positions, k_norm_w, k_trans, kp, NKV, NH * HD, 1);
  k_vproc<<<dim3(NKV, T_TOK), 64, 0, stream>>>(qkv, vp);
  k_attn<<<dim3(T_TOK / 64, NH), 256, 0, stream>>>(qp, kp, vp, ao);
  k_mix_quant<<<T_TOK, 256, 0, stream>>>(ao, o_trans, qo);
  k_gemm_bt<<<dim3(HID / 64, T_TOK / 64), 256, 0, stream>>>(qo, w_o, out, T_TOK, HID, HID);
}

// Round 3
// 3030.926 us; speedup vs baseline: 1.7910x; 1.7910x over previous
//
#include <hip/hip_runtime.h>
#include <math.h>

#define T_TOK 2048
#define HID   4096
#define NH    32
#define NKV   8
#define HD    128
#define QKVD  6144   // (NH + 2*NKV) * HD
#define V_OFF 5120   // NH*HD + NKV*HD

typedef __attribute__((ext_vector_type(8))) short short8;
typedef __attribute__((ext_vector_type(4))) float f32x4;

__device__ __forceinline__ unsigned short f2bf(float x) {
  unsigned u = __builtin_bit_cast(unsigned, x);
  u += 0x7fffu + ((u >> 16) & 1u);          // round-nearest-even
  return (unsigned short)(u >> 16);
}

// ---------------- wave helpers (wave64) ----------------
__device__ __forceinline__ float wave_sum(float v) {
  for (int off = 32; off; off >>= 1) v += __shfl_xor(v, off, 64);
  return v;
}
__device__ __forceinline__ float wave_max(float v) {
  for (int off = 32; off; off >>= 1) v = fmaxf(v, __shfl_xor(v, off, 64));
  return v;
}
__device__ __forceinline__ float wave_min(float v) {
  for (int off = 32; off; off >>= 1) v = fminf(v, __shfl_xor(v, off, 64));
  return v;
}

// ---------------- K1: bilinear (lnL^T X lnR) + 8-bit sym fake-quant per token ----------------
__global__ __launch_bounds__(256) void k_bilinear_quant(
    const float* __restrict__ hidden, const float* __restrict__ lnL,
    const float* __restrict__ lnR, float* __restrict__ xq)
{
  __shared__ float sX[4096];
  __shared__ float sT[4096];
  __shared__ float sL[4096];
  __shared__ float sR[4096];
  __shared__ float sm[4];
  const int t = blockIdx.x;
  const int tid = threadIdx.x;
  const float* src = hidden + (size_t)t * 4096;
  for (int i = tid; i < 4096; i += 256) { sX[i] = src[i]; sL[i] = lnL[i]; sR[i] = lnR[i]; }
  __syncthreads();
  #pragma unroll
  for (int u = 0; u < 16; u++) {
    int p = tid + 256 * u;
    int l = p >> 6, R = p & 63;
    float a = 0.f;
    #pragma unroll 8
    for (int r = 0; r < 64; r++) a += sX[(l << 6) + r] * sR[(r << 6) + R];
    sT[p] = a;
  }
  __syncthreads();
  float vals[16];
  float amax = 0.f;
  #pragma unroll
  for (int u = 0; u < 16; u++) {
    int p = tid + 256 * u;
    int L = p >> 6, R = p & 63;
    float a = 0.f;
    #pragma unroll 8
    for (int l = 0; l < 64; l++) a += sL[(l << 6) + L] * sT[(l << 6) + R];
    vals[u] = a;
    amax = fmaxf(amax, fabsf(a));
  }
  amax = wave_max(amax);
  if ((tid & 63) == 0) sm[tid >> 6] = amax;
  __syncthreads();
  amax = fmaxf(fmaxf(sm[0], sm[1]), fmaxf(sm[2], sm[3]));
  float scale = fmaxf(amax * (1.0f / 127.0f), 1e-8f);
  #pragma unroll
  for (int u = 0; u < 16; u++) {
    int p = tid + 256 * u;
    float q = rintf(vals[u] / scale);
    q = fminf(fmaxf(q, -128.f), 127.f);
    xq[(size_t)t * 4096 + p] = q * scale;
  }
}

// ---------------- GEMM: C[m][n] = sum_k A[m][k] * B[n][k] ----------------
__global__ __launch_bounds__(256) void k_gemm_bt(
    const float* __restrict__ A, const float* __restrict__ B, float* __restrict__ C,
    int M, int N, int K)
{
  __shared__ float sA[16][68];
  __shared__ float sB[16][68];
  const int tid = threadIdx.x;
  const int tx = tid & 15, ty = tid >> 4;
  const int bm = blockIdx.y << 6, bn = blockIdx.x << 6;
  const int lr = tid >> 2;
  const int lc = (tid & 3) << 2;
  const float* Ap = A + (size_t)(bm + lr) * K + lc;
  const float* Bp = B + (size_t)(bn + lr) * K + lc;
  float acc[4][4] = {{0.f}};
  for (int k0 = 0; k0 < K; k0 += 16) {
    float4 a4 = *(const float4*)(Ap + k0);
    float4 b4 = *(const float4*)(Bp + k0);
    __syncthreads();
    sA[lc + 0][lr] = a4.x; sA[lc + 1][lr] = a4.y; sA[lc + 2][lr] = a4.z; sA[lc + 3][lr] = a4.w;
    sB[lc + 0][lr] = b4.x; sB[lc + 1][lr] = b4.y; sB[lc + 2][lr] = b4.z; sB[lc + 3][lr] = b4.w;
    __syncthreads();
    #pragma unroll
    for (int k = 0; k < 16; k++) {
      float4 av = *(const float4*)&sA[k][ty << 2];
      float4 bv = *(const float4*)&sB[k][tx << 2];
      float am[4] = {av.x, av.y, av.z, av.w};
      float bb[4] = {bv.x, bv.y, bv.z, bv.w};
      #pragma unroll
      for (int i = 0; i < 4; i++)
        #pragma unroll
        for (int j = 0; j < 4; j++)
          acc[i][j] += am[i] * bb[j];
    }
  }
  #pragma unroll
  for (int i = 0; i < 4; i++) {
    float4 o; o.x = acc[i][0]; o.y = acc[i][1]; o.z = acc[i][2]; o.w = acc[i][3];
    *(float4*)(C + (size_t)(bm + (ty << 2) + i) * N + bn + (tx << 2)) = o;
  }
}

// ---------------- Q/K processing: rmsnorm -> rope -> @k_trans (-> 4-bit asym quant for K) ----------------
// one wave per (t, head); lane holds dims (lane, lane+64); bf16 output
__global__ __launch_bounds__(64) void k_qkproc(
    const float* __restrict__ qkv, const int* __restrict__ pos,
    const float* __restrict__ nw, const float* __restrict__ kt,
    unsigned short* __restrict__ dst_, int nheads, int off_n, int do_quant)
{
  const int h = blockIdx.x, t = blockIdx.y;
  const int lane = threadIdx.x;
  const float* src = qkv + (size_t)t * QKVD + off_n + h * HD;
  float x1 = src[lane], x2 = src[lane + 64];
  float ss = wave_sum(x1 * x1 + x2 * x2);
  float rinv = 1.0f / sqrtf(ss * (1.0f / 128.0f) + 1e-6f);
  x1 *= rinv * nw[lane];
  x2 *= rinv * nw[lane + 64];
  const float p = (float)pos[t];
  const float invf = exp2f((float)lane * (-19.931568569324174f / 64.0f)); // theta^{-j/64}
  const float fr = p * invf;
  const float c = cosf(fr), s = sinf(fr);
  const float y1 = x1 * c - x2 * s;
  const float y2 = x2 * c + x1 * s;
  __shared__ float sq[128];
  sq[lane] = y1; sq[lane + 64] = y2;
  __syncthreads();
  float o1 = 0.f, o2 = 0.f;
  #pragma unroll 8
  for (int e = 0; e < 128; e++) {
    float qe = sq[e];
    o1 += qe * kt[(e << 7) + lane];
    o2 += qe * kt[(e << 7) + 64 + lane];
  }
  if (do_quant) {  // 4-bit group-asym, group = 128 = whole head vector
    float mn = fminf(wave_min(fminf(o1, o2)), 0.f);
    float mx = fmaxf(wave_max(fmaxf(o1, o2)), 0.f);
    float scale = fmaxf((mx - mn) * (1.0f / 15.0f), 1e-8f);
    float zero = rintf(-mn / scale);
    float q1 = fminf(fmaxf(rintf(o1 / scale) + zero, 0.f), 15.f);
    float q2 = fminf(fmaxf(rintf(o2 / scale) + zero, 0.f), 15.f);
    o1 = (q1 - zero) * scale;
    o2 = (q2 - zero) * scale;
  }
  unsigned short* d = dst_ + ((size_t)t * nheads + h) * HD;
  d[lane] = f2bf(o1); d[lane + 64] = f2bf(o2);
}

// ---------------- V: 4-bit group-asym quant, output TRANSPOSED bf16 [kvh][d][t] ----------------
__global__ __launch_bounds__(256) void k_vproc(
    const float* __restrict__ qkv, unsigned short* __restrict__ vpT)
{
  __shared__ __align__(16) unsigned short sTt[128][72];
  const int kvh = blockIdx.x;
  const int t0  = blockIdx.y * 64;
  const int tid = threadIdx.x;
  const int tl = tid >> 2, part = tid & 3;   // 4 lanes per token
  const float* src = qkv + (size_t)(t0 + tl) * QKVD + V_OFF + kvh * HD + part * 32;
  float v[32];
  float mn = 0.f, mx = 0.f;                  // jnp: min(.,0) / max(.,0)
  #pragma unroll
  for (int c = 0; c < 8; c++) {
    float4 f = *(const float4*)(src + c * 4);
    v[c*4+0] = f.x; v[c*4+1] = f.y; v[c*4+2] = f.z; v[c*4+3] = f.w;
    mn = fminf(mn, fminf(fminf(f.x, f.y), fminf(f.z, f.w)));
    mx = fmaxf(mx, fmaxf(fmaxf(f.x, f.y), fmaxf(f.z, f.w)));
  }
  mn = fminf(mn, __shfl_xor(mn, 1, 64)); mn = fminf(mn, __shfl_xor(mn, 2, 64));
  mx = fmaxf(mx, __shfl_xor(mx, 1, 64)); mx = fmaxf(mx, __shfl_xor(mx, 2, 64));
  float scale = fmaxf((mx - mn) * (1.0f / 15.0f), 1e-8f);
  float zero  = rintf(-mn / scale);
  #pragma unroll
  for (int j = 0; j < 32; j++) {
    float q = fminf(fmaxf(rintf(v[j] / scale) + zero, 0.f), 15.f);
    sTt[part * 32 + j][tl] = f2bf((q - zero) * scale);
  }
  __syncthreads();
  // FIX (R2 bug): each row is 64 tokens = 8 float4s, not 4. Write all 8.
  for (int i = tid; i < 128 * 8; i += 256) {
    int d = i >> 3, seg = i & 7;
    *(float4*)(vpT + ((size_t)kvh * HD + d) * T_TOK + t0 + seg * 8) =
        *(const float4*)&sTt[d][seg * 8];
  }
}

// ---------------- MFMA flash attention, causal, GQA rep=4, bf16 in / f32 acc ----------------
// block = 4 waves = (head h, 64 q-rows); wave w owns rows q0+w*16 .. +15.
// frag maps (HW-verified): A/B idx=lane&15, k=(lane>>4)*8+j; C/D col=lane&15, row=(lane>>4)*4+reg
__global__ __launch_bounds__(256) void k_attn_mfma(
    const unsigned short* __restrict__ qp, const unsigned short* __restrict__ kp,
    const unsigned short* __restrict__ vpT, float* __restrict__ ao)
{
  __shared__ __align__(16) unsigned short sK[64][136];   // +8 pad: conflict-free b128 frags
  __shared__ __align__(16) unsigned short sVt[128][72];
  __shared__ __align__(16) unsigned short sP[4][16][72];
  const int qb = blockIdx.x, h = blockIdx.y;
  const int kvh = h >> 2;
  const int q0 = qb * 64;
  const int tid = threadIdx.x;
  const int w = tid >> 6;
  const int lane = tid & 63;
  const int n = lane & 15;
  const int quad = lane >> 4;

  // loop-invariant Q fragments straight from global (row = w*16 + n)
  short8 qfrag[4];
  {
    const unsigned short* qrow = qp + ((size_t)(q0 + w * 16 + n) * NH + h) * HD;
    #pragma unroll
    for (int kk = 0; kk < 4; kk++)
      qfrag[kk] = *(const short8*)(qrow + kk * 32 + quad * 8);
  }

  f32x4 oacc[8];
  #pragma unroll
  for (int dt = 0; dt < 8; dt++) oacc[dt] = (f32x4){0.f, 0.f, 0.f, 0.f};
  float m_i[4], l_i[4];
  #pragma unroll
  for (int r = 0; r < 4; r++) { m_i[r] = -1e30f; l_i[r] = 0.f; }

  const float sm_scale = 0.08838834764831845f;  // 128^-0.5
  const float LOG2E = 1.4426950408889634f;

  for (int s0 = 0; s0 <= q0; s0 += 64) {
    __syncthreads();
    for (int i = tid; i < 1024; i += 256) {            // K tile 64x128
      int row = i >> 4, ch = i & 15;
      *(float4*)&sK[row][ch * 8] =
          *(const float4*)(kp + ((size_t)(s0 + row) * NKV + kvh) * HD + ch * 8);
    }
    for (int i = tid; i < 1024; i += 256) {            // V^T tile 128x64
      int row = i >> 3, ch = i & 7;
      *(float4*)&sVt[row][ch * 8] =
          *(const float4*)(vpT + ((size_t)kvh * HD + row) * T_TOK + s0 + ch * 8);
    }
    __syncthreads();

    // S = Q K^T : 16x64 per wave
    f32x4 sacc[4];
    #pragma unroll
    for (int jt = 0; jt < 4; jt++) {
      f32x4 c = (f32x4){0.f, 0.f, 0.f, 0.f};
      #pragma unroll
      for (int kk = 0; kk < 4; kk++) {
        short8 b = *(const short8*)&sK[jt * 16 + n][kk * 32 + quad * 8];
        c = __builtin_amdgcn_mfma_f32_16x16x32_bf16(qfrag[kk], b, c, 0, 0, 0);
      }
      sacc[jt] = c;
    }

    // online softmax (row = quad*4 + r)
    float mx[4] = {-1e30f, -1e30f, -1e30f, -1e30f};
    #pragma unroll
    for (int jt = 0; jt < 4; jt++) {
      #pragma unroll
      for (int r = 0; r < 4; r++) {
        int sg = s0 + jt * 16 + n;
        int ig = q0 + w * 16 + quad * 4 + r;
        float v = (sg <= ig) ? sacc[jt][r] * sm_scale : -1e30f;
        sacc[jt][r] = v;
        mx[r] = fmaxf(mx[r], v);
      }
    }
    #pragma unroll
    for (int off = 1; off < 16; off <<= 1)
      #pragma unroll
      for (int r = 0; r < 4; r++) mx[r] = fmaxf(mx[r], __shfl_xor(mx[r], off, 64));
    float alpha[4], psum[4];
    #pragma unroll
    for (int r = 0; r < 4; r++) {
      float m_new = fmaxf(m_i[r], mx[r]);
      alpha[r] = exp2f((m_i[r] - m_new) * LOG2E);
      m_i[r] = m_new;
      psum[r] = 0.f;
    }
    #pragma unroll
    for (int jt = 0; jt < 4; jt++) {
      #pragma unroll
      for (int r = 0; r < 4; r++) {
        float pv = exp2f((sacc[jt][r] - m_i[r]) * LOG2E);
        psum[r] += pv;
        sP[w][quad * 4 + r][jt * 16 + n] = f2bf(pv);
      }
    }
    #pragma unroll
    for (int off = 1; off < 16; off <<= 1)
      #pragma unroll
      for (int r = 0; r < 4; r++) psum[r] += __shfl_xor(psum[r], off, 64);
    #pragma unroll
    for (int r = 0; r < 4; r++) l_i[r] = l_i[r] * alpha[r] + psum[r];
    #pragma unroll
    for (int dt = 0; dt < 8; dt++)
      #pragma unroll
      for (int r = 0; r < 4; r++) oacc[dt][r] *= alpha[r];
    __syncthreads();  // sP visible (also orders vs next staging)

    // O += P V : P A-frags from LDS round-trip, V^T B-frags
    short8 pfrag[2];
    #pragma unroll
    for (int kk = 0; kk < 2; kk++)
      pfrag[kk] = *(const short8*)&sP[w][n][kk * 32 + quad * 8];
    #pragma unroll
    for (int dt = 0; dt < 8; dt++) {
      f32x4 c = oacc[dt];
      #pragma unroll
      for (int kk = 0; kk < 2; kk++) {
        short8 b = *(const short8*)&sVt[dt * 16 + n][kk * 32 + quad * 8];
        c = __builtin_amdgcn_mfma_f32_16x16x32_bf16(pfrag[kk], b, c, 0, 0, 0);
      }
      oacc[dt] = c;
    }
  }

  #pragma unroll
  for (int r = 0; r < 4; r++) {
    float linv = 1.0f / l_i[r];
    int t = q0 + w * 16 + quad * 4 + r;
    float* dst = ao + (size_t)t * (NH * HD) + h * HD;
    #pragma unroll
    for (int dt = 0; dt < 8; dt++)
      dst[dt * 16 + n] = oacc[dt][r] * linv;
  }
}

// ---------------- head mix (o_trans^T over heads) + 8-bit sym fake-quant per token ----------------
__global__ __launch_bounds__(256) void k_mix_quant(
    const float* __restrict__ ao, const float* __restrict__ ot, float* __restrict__ qo)
{
  __shared__ float sA[4096];
  __shared__ float sO[1024];
  __shared__ float sm[4];
  const int t = blockIdx.x;
  const int tid = threadIdx.x;
  for (int i = tid; i < 4096; i += 256) sA[i] = ao[(size_t)t * 4096 + i];
  for (int i = tid; i < 1024; i += 256) sO[i] = ot[i];
  __syncthreads();
  float vals[16];
  float amax = 0.f;
  #pragma unroll
  for (int u = 0; u < 16; u++) {
    int o = tid + 256 * u;
    int ih = o >> 7, d = o & 127;
    float a = 0.f;
    #pragma unroll 8
    for (int j = 0; j < 32; j++) a += sO[j * 32 + ih] * sA[j * 128 + d];
    vals[u] = a;
    amax = fmaxf(amax, fabsf(a));
  }
  amax = wave_max(amax);
  if ((tid & 63) == 0) sm[tid >> 6] = amax;
  __syncthreads();
  amax = fmaxf(fmaxf(sm[0], sm[1]), fmaxf(sm[2], sm[3]));
  float scale = fmaxf(amax * (1.0f / 127.0f), 1e-8f);
  #pragma unroll
  for (int u = 0; u < 16; u++) {
    int o = tid + 256 * u;
    float q = rintf(vals[u] / scale);
    q = fminf(fmaxf(q, -128.f), 127.f);
    qo[(size_t)t * 4096 + o] = q * scale;
  }
}

extern "C" void kernel_launch(void* const* d_in, const int* in_sizes, int n_in,
                              void* d_out, int out_size, void* d_ws, size_t ws_size,
                              hipStream_t stream) {
  const float* hidden    = (const float*)d_in[0];
  const int*   positions = (const int*)  d_in[1];
  const float* w_qkv     = (const float*)d_in[2];
  const float* w_o       = (const float*)d_in[3];
  const float* q_norm_w  = (const float*)d_in[4];
  const float* k_norm_w  = (const float*)d_in[5];
  const float* ln_left   = (const float*)d_in[6];
  const float* ln_right  = (const float*)d_in[7];
  const float* o_trans   = (const float*)d_in[8];
  const float* k_trans   = (const float*)d_in[9];
  float* out = (float*)d_out;
  char* ws = (char*)d_ws;

  // workspace layout (peak 108 MiB):
  float*          xq  = (float*)(ws);                       // 32 MiB (T x 4096) -> reused as ao
  float*          qkv = (float*)(ws + 33554432);            // 48 MiB (T x 6144) -> reused as qo
  unsigned short* qp  = (unsigned short*)(ws + 83886080);   // 16 MiB bf16 (T x 32 x 128)
  unsigned short* kp  = (unsigned short*)(ws + 100663296);  //  4 MiB bf16 (T x 8 x 128)
  unsigned short* vpT = (unsigned short*)(ws + 104857600);  //  4 MiB bf16 (8 x 128 x T)
  float* ao = xq;
  float* qo = qkv;

  k_bilinear_quant<<<T_TOK, 256, 0, stream>>>(hidden, ln_left, ln_right, xq);
  k_gemm_bt<<<dim3(QKVD / 64, T_TOK / 64), 256, 0, stream>>>(xq, w_qkv, qkv, T_TOK, QKVD, HID);
  k_qkproc<<<dim3(NH, T_TOK), 64, 0, stream>>>(qkv, positions, q_norm_w, k_trans, qp, NH, 0, 0);
  k_qkproc<<<dim3(NKV, T_TOK), 64, 0, stream>>>(qkv, positions, k_norm_w, k_trans, kp, NKV, NH * HD, 1);
  k_vproc<<<dim3(NKV, T_TOK / 64), 256, 0, stream>>>(qkv, vpT);
  k_attn_mfma<<<dim3(T_TOK / 64, NH), 256, 0, stream>>>(qp, kp, vpT, ao);
  k_mix_quant<<<T_TOK, 256, 0, stream>>>(ao, o_trans, qo);
  k_gemm_bt<<<dim3(HID / 64, T_TOK / 64), 256, 0, stream>>>(qo, w_o, out, T_TOK, HID, HID);
}

// Round 5
// 1102.554 us; speedup vs baseline: 4.9235x; 2.7490x over previous
//
#include <hip/hip_runtime.h>
#include <math.h>

#define T_TOK 2048
#define HID   4096
#define NH    32
#define NKV   8
#define HD    128
#define QKVD  6144   // (NH + 2*NKV) * HD
#define V_OFF 5120   // NH*HD + NKV*HD

typedef __attribute__((ext_vector_type(8))) short short8;
typedef __attribute__((ext_vector_type(4))) short s4v;
typedef __attribute__((ext_vector_type(4))) float f32x4;

__device__ __forceinline__ unsigned short f2bf(float x) {
  unsigned u = __builtin_bit_cast(unsigned, x);
  u += 0x7fffu + ((u >> 16) & 1u);          // round-nearest-even
  return (unsigned short)(u >> 16);
}
__device__ __forceinline__ float bf2f(unsigned short h) {
  unsigned u = ((unsigned)h) << 16;
  return __builtin_bit_cast(float, u);
}

// global -> LDS direct DMA, 16 B per lane
__device__ __forceinline__ void g2lds16(const void* g, void* l) {
  __builtin_amdgcn_global_load_lds(
      (const __attribute__((address_space(1))) unsigned int*)g,
      (__attribute__((address_space(3))) unsigned int*)(unsigned int)(unsigned long long)l,
      16, 0, 0);
}

// ---------------- wave helpers (wave64) ----------------
__device__ __forceinline__ float wave_sum(float v) {
  for (int off = 32; off; off >>= 1) v += __shfl_xor(v, off, 64);
  return v;
}
__device__ __forceinline__ float wave_max(float v) {
  for (int off = 32; off; off >>= 1) v = fmaxf(v, __shfl_xor(v, off, 64));
  return v;
}
__device__ __forceinline__ float wave_min(float v) {
  for (int off = 32; off; off >>= 1) v = fminf(v, __shfl_xor(v, off, 64));
  return v;
}

// ---------------- f32 -> bf16 weight conversion (memory-bound) ----------------
__global__ __launch_bounds__(256) void k_f32_to_bf16(
    const float* __restrict__ s, unsigned short* __restrict__ d, int n8)
{
  int i = blockIdx.x * 256 + threadIdx.x;
  if (i >= n8) return;
  const float4* sp = (const float4*)s + (size_t)i * 2;
  float4 a = sp[0], b = sp[1];
  short8 o;
  o[0] = f2bf(a.x); o[1] = f2bf(a.y); o[2] = f2bf(a.z); o[3] = f2bf(a.w);
  o[4] = f2bf(b.x); o[5] = f2bf(b.y); o[6] = f2bf(b.z); o[7] = f2bf(b.w);
  *(short8*)(d + (size_t)i * 8) = o;
}

// ---------------- K1: bilinear (lnL^T X lnR) + 8-bit sym fake-quant ----------------
// outputs INTEGER q as bf16 (exact, |q|<=128) + per-token f32 scale
__global__ __launch_bounds__(256) void k_bilinear_quant(
    const float* __restrict__ hidden, const float* __restrict__ lnL,
    const float* __restrict__ lnR, unsigned short* __restrict__ xqb,
    float* __restrict__ scales)
{
  __shared__ float sX[4096];
  __shared__ float sT[4096];
  __shared__ float sL[4096];
  __shared__ float sR[4096];
  __shared__ float sm[4];
  const int t = blockIdx.x;
  const int tid = threadIdx.x;
  const float* src = hidden + (size_t)t * 4096;
  for (int i = tid; i < 4096; i += 256) { sX[i] = src[i]; sL[i] = lnL[i]; sR[i] = lnR[i]; }
  __syncthreads();
  #pragma unroll
  for (int u = 0; u < 16; u++) {
    int p = tid + 256 * u;
    int l = p >> 6, R = p & 63;
    float a = 0.f;
    #pragma unroll 8
    for (int r = 0; r < 64; r++) a += sX[(l << 6) + r] * sR[(r << 6) + R];
    sT[p] = a;
  }
  __syncthreads();
  float vals[16];
  float amax = 0.f;
  #pragma unroll
  for (int u = 0; u < 16; u++) {
    int p = tid + 256 * u;
    int L = p >> 6, R = p & 63;
    float a = 0.f;
    #pragma unroll 8
    for (int l = 0; l < 64; l++) a += sL[(l << 6) + L] * sT[(l << 6) + R];
    vals[u] = a;
    amax = fmaxf(amax, fabsf(a));
  }
  amax = wave_max(amax);
  if ((tid & 63) == 0) sm[tid >> 6] = amax;
  __syncthreads();
  amax = fmaxf(fmaxf(sm[0], sm[1]), fmaxf(sm[2], sm[3]));
  float scale = fmaxf(amax * (1.0f / 127.0f), 1e-8f);
  if (tid == 0) scales[t] = scale;
  #pragma unroll
  for (int u = 0; u < 16; u++) {
    int p = tid + 256 * u;
    float q = rintf(vals[u] / scale);
    q = fminf(fmaxf(q, -128.f), 127.f);
    xqb[(size_t)t * 4096 + p] = f2bf(q);   // exact integer in bf16
  }
}

// ---------------- split-precision MFMA GEMM (QKV): C = scale[m] * A @ Bf^T ----------------
// A bf16 exact ints [M][K]; Bf f32 [N][K] split on the fly into bf16 hi+lo.
// Error ~ f32 noise floor (residual <= 2^-18 |w|). 128x128 tile, BK=32, 2x MFMA.
__global__ __launch_bounds__(256) void k_gemm_split(
    const unsigned short* __restrict__ A, const float* __restrict__ Bf,
    const float* __restrict__ scales, float* __restrict__ C, int N, int K)
{
  __shared__ __align__(16) unsigned short sA[128 * 32];
  __shared__ __align__(16) unsigned short sBh[128 * 32];
  __shared__ __align__(16) unsigned short sBl[128 * 32];
  __shared__ float sS[128];
  const int tid = threadIdx.x;
  const int w = tid >> 6, lane = tid & 63;
  const int n16 = lane & 15, quad = lane >> 4;
  const int bm = blockIdx.y << 7, bn = blockIdx.x << 7;
  const int wm = (w >> 1) << 6, wn = (w & 1) << 6;
  if (tid < 128) sS[tid] = scales[bm + tid];
  const int srow = lane >> 2;          // A staging: 16 rows per wave-load
  const int scol = (lane & 3) << 3;    // 8 bf16 per lane
  f32x4 acc[4][4];
  #pragma unroll
  for (int i = 0; i < 4; i++)
    #pragma unroll
    for (int j = 0; j < 4; j++) acc[i][j] = (f32x4){0.f, 0.f, 0.f, 0.f};

  for (int k0 = 0; k0 < K; k0 += 32) {
    __syncthreads();
    // A: global_load_lds DMA
    #pragma unroll
    for (int r = 0; r < 2; r++) {
      const int grp = (r << 2) + w;
      const int row = (grp << 4) + srow;
      g2lds16(A + (size_t)(bm + row) * K + k0 + scol, &sA[(grp << 9) + lane * 8]);
    }
    // B: f32 through registers -> hi/lo bf16 tiles (coalesced float4 reads)
    #pragma unroll
    for (int it = 0; it < 4; it++) {
      int idx = it * 256 + tid;
      int row = idx >> 3, c4 = (idx & 7) << 2;
      float4 f = *(const float4*)(Bf + (size_t)(bn + row) * K + k0 + c4);
      unsigned short h0 = f2bf(f.x), h1 = f2bf(f.y), h2 = f2bf(f.z), h3 = f2bf(f.w);
      *(s4v*)&sBh[row * 32 + c4] = (s4v){(short)h0, (short)h1, (short)h2, (short)h3};
      *(s4v*)&sBl[row * 32 + c4] = (s4v){
          (short)f2bf(f.x - bf2f(h0)), (short)f2bf(f.y - bf2f(h1)),
          (short)f2bf(f.z - bf2f(h2)), (short)f2bf(f.w - bf2f(h3))};
    }
    __syncthreads();
    short8 af[4], bh[4], bl[4];
    #pragma unroll
    for (int t = 0; t < 4; t++) {
      af[t] = *(const short8*)&sA [(wm + (t << 4) + n16) * 32 + (quad << 3)];
      bh[t] = *(const short8*)&sBh[(wn + (t << 4) + n16) * 32 + (quad << 3)];
      bl[t] = *(const short8*)&sBl[(wn + (t << 4) + n16) * 32 + (quad << 3)];
    }
    #pragma unroll
    for (int i = 0; i < 4; i++)
      #pragma unroll
      for (int j = 0; j < 4; j++) {
        acc[i][j] = __builtin_amdgcn_mfma_f32_16x16x32_bf16(af[i], bh[j], acc[i][j], 0, 0, 0);
        acc[i][j] = __builtin_amdgcn_mfma_f32_16x16x32_bf16(af[i], bl[j], acc[i][j], 0, 0, 0);
      }
  }

  #pragma unroll
  for (int i = 0; i < 4; i++) {
    #pragma unroll
    for (int r = 0; r < 4; r++) {
      int lrow = wm + (i << 4) + (quad << 2) + r;
      float s = sS[lrow];
      float* crow = C + (size_t)(bm + lrow) * N + bn + wn;
      #pragma unroll
      for (int j = 0; j < 4; j++)
        crow[(j << 4) + n16] = acc[i][j][r] * s;
    }
  }
}

// ---------------- MFMA GEMM (out-proj): C[m][n] = scale[m] * sum_k A[m][k]*B[n][k] ----------------
__global__ __launch_bounds__(256) void k_gemm_mfma(
    const unsigned short* __restrict__ A, const unsigned short* __restrict__ Bm,
    const float* __restrict__ scales, float* __restrict__ C, int N, int K)
{
  __shared__ __align__(16) unsigned short sA[128 * 32];
  __shared__ __align__(16) unsigned short sB[128 * 32];
  __shared__ float sS[128];
  const int tid = threadIdx.x;
  const int w = tid >> 6, lane = tid & 63;
  const int n16 = lane & 15, quad = lane >> 4;
  const int bm = blockIdx.y << 7, bn = blockIdx.x << 7;
  const int wm = (w >> 1) << 6, wn = (w & 1) << 6;
  if (tid < 128) sS[tid] = scales[bm + tid];
  const int srow = lane >> 2;
  const int scol = (lane & 3) << 3;
  f32x4 acc[4][4];
  #pragma unroll
  for (int i = 0; i < 4; i++)
    #pragma unroll
    for (int j = 0; j < 4; j++) acc[i][j] = (f32x4){0.f, 0.f, 0.f, 0.f};

  for (int k0 = 0; k0 < K; k0 += 32) {
    __syncthreads();
    #pragma unroll
    for (int r = 0; r < 2; r++) {
      const int grp = (r << 2) + w;
      const int row = (grp << 4) + srow;
      g2lds16(A  + (size_t)(bm + row) * K + k0 + scol, &sA[(grp << 9) + lane * 8]);
      g2lds16(Bm + (size_t)(bn + row) * K + k0 + scol, &sB[(grp << 9) + lane * 8]);
    }
    __syncthreads();
    short8 af[4], bfr[4];
    #pragma unroll
    for (int t = 0; t < 4; t++) {
      af[t]  = *(const short8*)&sA[(wm + (t << 4) + n16) * 32 + (quad << 3)];
      bfr[t] = *(const short8*)&sB[(wn + (t << 4) + n16) * 32 + (quad << 3)];
    }
    #pragma unroll
    for (int i = 0; i < 4; i++)
      #pragma unroll
      for (int j = 0; j < 4; j++)
        acc[i][j] = __builtin_amdgcn_mfma_f32_16x16x32_bf16(af[i], bfr[j], acc[i][j], 0, 0, 0);
  }

  #pragma unroll
  for (int i = 0; i < 4; i++) {
    #pragma unroll
    for (int r = 0; r < 4; r++) {
      int lrow = wm + (i << 4) + (quad << 2) + r;
      float s = sS[lrow];
      float* crow = C + (size_t)(bm + lrow) * N + bn + wn;
      #pragma unroll
      for (int j = 0; j < 4; j++)
        crow[(j << 4) + n16] = acc[i][j][r] * s;
    }
  }
}

// ---------------- Q/K processing: rmsnorm -> rope -> @k_trans (-> 4-bit asym quant for K) ----------------
__global__ __launch_bounds__(64) void k_qkproc(
    const float* __restrict__ qkv, const int* __restrict__ pos,
    const float* __restrict__ nw, const float* __restrict__ kt,
    unsigned short* __restrict__ dst_, int nheads, int off_n, int do_quant)
{
  const int h = blockIdx.x, t = blockIdx.y;
  const int lane = threadIdx.x;
  const float* src = qkv + (size_t)t * QKVD + off_n + h * HD;
  float x1 = src[lane], x2 = src[lane + 64];
  float ss = wave_sum(x1 * x1 + x2 * x2);
  float rinv = 1.0f / sqrtf(ss * (1.0f / 128.0f) + 1e-6f);
  x1 *= rinv * nw[lane];
  x2 *= rinv * nw[lane + 64];
  const float p = (float)pos[t];
  const float invf = exp2f((float)lane * (-19.931568569324174f / 64.0f)); // theta^{-j/64}
  const float fr = p * invf;
  const float c = cosf(fr), s = sinf(fr);
  const float y1 = x1 * c - x2 * s;
  const float y2 = x2 * c + x1 * s;
  __shared__ float sq[128];
  sq[lane] = y1; sq[lane + 64] = y2;
  __syncthreads();
  float o1 = 0.f, o2 = 0.f;
  #pragma unroll 8
  for (int e = 0; e < 128; e++) {
    float qe = sq[e];
    o1 += qe * kt[(e << 7) + lane];
    o2 += qe * kt[(e << 7) + 64 + lane];
  }
  if (do_quant) {
    float mn = fminf(wave_min(fminf(o1, o2)), 0.f);
    float mx = fmaxf(wave_max(fmaxf(o1, o2)), 0.f);
    float scale = fmaxf((mx - mn) * (1.0f / 15.0f), 1e-8f);
    float zero = rintf(-mn / scale);
    float q1 = fminf(fmaxf(rintf(o1 / scale) + zero, 0.f), 15.f);
    float q2 = fminf(fmaxf(rintf(o2 / scale) + zero, 0.f), 15.f);
    o1 = (q1 - zero) * scale;
    o2 = (q2 - zero) * scale;
  }
  unsigned short* d = dst_ + ((size_t)t * nheads + h) * HD;
  d[lane] = f2bf(o1); d[lane + 64] = f2bf(o2);
}

// ---------------- V: 4-bit group-asym quant, output TRANSPOSED bf16 [kvh][d][t] ----------------
__global__ __launch_bounds__(256) void k_vproc(
    const float* __restrict__ qkv, unsigned short* __restrict__ vpT)
{
  __shared__ __align__(16) unsigned short sTt[128][72];
  const int kvh = blockIdx.x;
  const int t0  = blockIdx.y * 64;
  const int tid = threadIdx.x;
  const int tl = tid >> 2, part = tid & 3;
  const float* src = qkv + (size_t)(t0 + tl) * QKVD + V_OFF + kvh * HD + part * 32;
  float v[32];
  float mn = 0.f, mx = 0.f;
  #pragma unroll
  for (int c = 0; c < 8; c++) {
    float4 f = *(const float4*)(src + c * 4);
    v[c*4+0] = f.x; v[c*4+1] = f.y; v[c*4+2] = f.z; v[c*4+3] = f.w;
    mn = fminf(mn, fminf(fminf(f.x, f.y), fminf(f.z, f.w)));
    mx = fmaxf(mx, fmaxf(fmaxf(f.x, f.y), fmaxf(f.z, f.w)));
  }
  mn = fminf(mn, __shfl_xor(mn, 1, 64)); mn = fminf(mn, __shfl_xor(mn, 2, 64));
  mx = fmaxf(mx, __shfl_xor(mx, 1, 64)); mx = fmaxf(mx, __shfl_xor(mx, 2, 64));
  float scale = fmaxf((mx - mn) * (1.0f / 15.0f), 1e-8f);
  float zero  = rintf(-mn / scale);
  #pragma unroll
  for (int j = 0; j < 32; j++) {
    float q = fminf(fmaxf(rintf(v[j] / scale) + zero, 0.f), 15.f);
    sTt[part * 32 + j][tl] = f2bf((q - zero) * scale);
  }
  __syncthreads();
  for (int i = tid; i < 128 * 8; i += 256) {
    int d = i >> 3, seg = i & 7;
    *(float4*)(vpT + ((size_t)kvh * HD + d) * T_TOK + t0 + seg * 8) =
        *(const float4*)&sTt[d][seg * 8];
  }
}

// ---------------- MFMA flash attention, causal, GQA rep=4, bf16 in / f32 acc ----------------
__global__ __launch_bounds__(256) void k_attn_mfma(
    const unsigned short* __restrict__ qp, const unsigned short* __restrict__ kp,
    const unsigned short* __restrict__ vpT, float* __restrict__ ao)
{
  __shared__ __align__(16) unsigned short sK[64][136];
  __shared__ __align__(16) unsigned short sVt[128][72];
  __shared__ __align__(16) unsigned short sP[4][16][72];
  const int qb = blockIdx.x, h = blockIdx.y;
  const int kvh = h >> 2;
  const int q0 = qb * 64;
  const int tid = threadIdx.x;
  const int w = tid >> 6;
  const int lane = tid & 63;
  const int n = lane & 15;
  const int quad = lane >> 4;

  short8 qfrag[4];
  {
    const unsigned short* qrow = qp + ((size_t)(q0 + w * 16 + n) * NH + h) * HD;
    #pragma unroll
    for (int kk = 0; kk < 4; kk++)
      qfrag[kk] = *(const short8*)(qrow + kk * 32 + quad * 8);
  }

  f32x4 oacc[8];
  #pragma unroll
  for (int dt = 0; dt < 8; dt++) oacc[dt] = (f32x4){0.f, 0.f, 0.f, 0.f};
  float m_i[4], l_i[4];
  #pragma unroll
  for (int r = 0; r < 4; r++) { m_i[r] = -1e30f; l_i[r] = 0.f; }

  const float sm_scale = 0.08838834764831845f;
  const float LOG2E = 1.4426950408889634f;

  for (int s0 = 0; s0 <= q0; s0 += 64) {
    __syncthreads();
    for (int i = tid; i < 1024; i += 256) {
      int row = i >> 4, ch = i & 15;
      *(float4*)&sK[row][ch * 8] =
          *(const float4*)(kp + ((size_t)(s0 + row) * NKV + kvh) * HD + ch * 8);
    }
    for (int i = tid; i < 1024; i += 256) {
      int row = i >> 3, ch = i & 7;
      *(float4*)&sVt[row][ch * 8] =
          *(const float4*)(vpT + ((size_t)kvh * HD + row) * T_TOK + s0 + ch * 8);
    }
    __syncthreads();

    f32x4 sacc[4];
    #pragma unroll
    for (int jt = 0; jt < 4; jt++) {
      f32x4 c = (f32x4){0.f, 0.f, 0.f, 0.f};
      #pragma unroll
      for (int kk = 0; kk < 4; kk++) {
        short8 b = *(const short8*)&sK[jt * 16 + n][kk * 32 + quad * 8];
        c = __builtin_amdgcn_mfma_f32_16x16x32_bf16(qfrag[kk], b, c, 0, 0, 0);
      }
      sacc[jt] = c;
    }

    float mx[4] = {-1e30f, -1e30f, -1e30f, -1e30f};
    #pragma unroll
    for (int jt = 0; jt < 4; jt++) {
      #pragma unroll
      for (int r = 0; r < 4; r++) {
        int sg = s0 + jt * 16 + n;
        int ig = q0 + w * 16 + quad * 4 + r;
        float v = (sg <= ig) ? sacc[jt][r] * sm_scale : -1e30f;
        sacc[jt][r] = v;
        mx[r] = fmaxf(mx[r], v);
      }
    }
    #pragma unroll
    for (int off = 1; off < 16; off <<= 1)
      #pragma unroll
      for (int r = 0; r < 4; r++) mx[r] = fmaxf(mx[r], __shfl_xor(mx[r], off, 64));
    float alpha[4], psum[4];
    #pragma unroll
    for (int r = 0; r < 4; r++) {
      float m_new = fmaxf(m_i[r], mx[r]);
      alpha[r] = exp2f((m_i[r] - m_new) * LOG2E);
      m_i[r] = m_new;
      psum[r] = 0.f;
    }
    #pragma unroll
    for (int jt = 0; jt < 4; jt++) {
      #pragma unroll
      for (int r = 0; r < 4; r++) {
        float pv = exp2f((sacc[jt][r] - m_i[r]) * LOG2E);
        psum[r] += pv;
        sP[w][quad * 4 + r][jt * 16 + n] = f2bf(pv);
      }
    }
    #pragma unroll
    for (int off = 1; off < 16; off <<= 1)
      #pragma unroll
      for (int r = 0; r < 4; r++) psum[r] += __shfl_xor(psum[r], off, 64);
    #pragma unroll
    for (int r = 0; r < 4; r++) l_i[r] = l_i[r] * alpha[r] + psum[r];
    #pragma unroll
    for (int dt = 0; dt < 8; dt++)
      #pragma unroll
      for (int r = 0; r < 4; r++) oacc[dt][r] *= alpha[r];
    __syncthreads();

    short8 pfrag[2];
    #pragma unroll
    for (int kk = 0; kk < 2; kk++)
      pfrag[kk] = *(const short8*)&sP[w][n][kk * 32 + quad * 8];
    #pragma unroll
    for (int dt = 0; dt < 8; dt++) {
      f32x4 c = oacc[dt];
      #pragma unroll
      for (int kk = 0; kk < 2; kk++) {
        short8 b = *(const short8*)&sVt[dt * 16 + n][kk * 32 + quad * 8];
        c = __builtin_amdgcn_mfma_f32_16x16x32_bf16(pfrag[kk], b, c, 0, 0, 0);
      }
      oacc[dt] = c;
    }
  }

  #pragma unroll
  for (int r = 0; r < 4; r++) {
    float linv = 1.0f / l_i[r];
    int t = q0 + w * 16 + quad * 4 + r;
    float* dst = ao + (size_t)t * (NH * HD) + h * HD;
    #pragma unroll
    for (int dt = 0; dt < 8; dt++)
      dst[dt * 16 + n] = oacc[dt][r] * linv;
  }
}

// ---------------- head mix + 8-bit sym fake-quant: INTEGER bf16 out + scale ----------------
__global__ __launch_bounds__(256) void k_mix_quant(
    const float* __restrict__ ao, const float* __restrict__ ot,
    unsigned short* __restrict__ qob, float* __restrict__ scales)
{
  __shared__ float sA[4096];
  __shared__ float sO[1024];
  __shared__ float sm[4];
  const int t = blockIdx.x;
  const int tid = threadIdx.x;
  for (int i = tid; i < 4096; i += 256) sA[i] = ao[(size_t)t * 4096 + i];
  for (int i = tid; i < 1024; i += 256) sO[i] = ot[i];
  __syncthreads();
  float vals[16];
  float amax = 0.f;
  #pragma unroll
  for (int u = 0; u < 16; u++) {
    int o = tid + 256 * u;
    int ih = o >> 7, d = o & 127;
    float a = 0.f;
    #pragma unroll 8
    for (int j = 0; j < 32; j++) a += sO[j * 32 + ih] * sA[j * 128 + d];
    vals[u] = a;
    amax = fmaxf(amax, fabsf(a));
  }
  amax = wave_max(amax);
  if ((tid & 63) == 0) sm[tid >> 6] = amax;
  __syncthreads();
  amax = fmaxf(fmaxf(sm[0], sm[1]), fmaxf(sm[2], sm[3]));
  float scale = fmaxf(amax * (1.0f / 127.0f), 1e-8f);
  if (tid == 0) scales[t] = scale;
  #pragma unroll
  for (int u = 0; u < 16; u++) {
    int o = tid + 256 * u;
    float q = rintf(vals[u] / scale);
    q = fminf(fmaxf(q, -128.f), 127.f);
    qob[(size_t)t * 4096 + o] = f2bf(q);
  }
}

extern "C" void kernel_launch(void* const* d_in, const int* in_sizes, int n_in,
                              void* d_out, int out_size, void* d_ws, size_t ws_size,
                              hipStream_t stream) {
  const float* hidden    = (const float*)d_in[0];
  const int*   positions = (const int*)  d_in[1];
  const float* w_qkv     = (const float*)d_in[2];
  const float* w_o       = (const float*)d_in[3];
  const float* q_norm_w  = (const float*)d_in[4];
  const float* k_norm_w  = (const float*)d_in[5];
  const float* ln_left   = (const float*)d_in[6];
  const float* ln_right  = (const float*)d_in[7];
  const float* o_trans   = (const float*)d_in[8];
  const float* k_trans   = (const float*)d_in[9];
  float* out = (float*)d_out;
  char* ws = (char*)d_ws;

  // workspace layout, peak 120 MiB:
  float*          qkv  = (float*)(ws);                       // 48 MiB f32 (T x 6144); reused as ao (32 MiB)
  unsigned short* xqb  = (unsigned short*)(ws + 50331648);   // 16 MiB bf16 int A1; reused as qob (A2)
  float*          sc1  = (float*)(ws + 67108864);            // 8 KiB
  float*          sc2  = (float*)(ws + 67117056);            // 8 KiB
  unsigned short* qp   = (unsigned short*)(ws + 67125248);   // 16 MiB bf16 (T x 32 x 128)
  unsigned short* kp   = (unsigned short*)(ws + 83902464);   //  4 MiB bf16 (T x 8 x 128)
  unsigned short* vpT  = (unsigned short*)(ws + 88096768);   //  4 MiB bf16 (8 x 128 x T)
  unsigned short* wob  = (unsigned short*)(ws + 92291072);   // 32 MiB bf16 w_o
  float*          ao   = qkv;
  unsigned short* qob  = xqb;

  k_bilinear_quant<<<T_TOK, 256, 0, stream>>>(hidden, ln_left, ln_right, xqb, sc1);
  k_gemm_split<<<dim3(QKVD / 128, T_TOK / 128), 256, 0, stream>>>(xqb, w_qkv, sc1, qkv, QKVD, HID);
  k_qkproc<<<dim3(NH, T_TOK), 64, 0, stream>>>(qkv, positions, q_norm_w, k_trans, qp, NH, 0, 0);
  k_qkproc<<<dim3(NKV, T_TOK), 64, 0, stream>>>(qkv, positions, k_norm_w, k_trans, kp, NKV, NH * HD, 1);
  k_vproc<<<dim3(NKV, T_TOK / 64), 256, 0, stream>>>(qkv, vpT);
  k_f32_to_bf16<<<(HID * HID / 8 + 255) / 256, 256, 0, stream>>>(w_o, wob, HID * HID / 8);
  k_attn_mfma<<<dim3(T_TOK / 64, NH), 256, 0, stream>>>(qp, kp, vpT, ao);   // qkv dead now
  k_mix_quant<<<T_TOK, 256, 0, stream>>>(ao, o_trans, qob, sc2);            // xqb dead now
  k_gemm_mfma<<<dim3(HID / 128, T_TOK / 128), 256, 0, stream>>>(qob, wob, sc2, out, HID, HID);
}